// Round 10
// baseline (610.378 us; speedup 1.0000x reference)
//
#include <hip/hip_runtime.h>

typedef short s8v __attribute__((ext_vector_type(8)));
typedef short s4v __attribute__((ext_vector_type(4)));
typedef float f4v __attribute__((ext_vector_type(4)));

#define LQ 1568
#define LK 1568
#define NH 12
#define LQP 1664   // 13*128 padded q-rows per head

__device__ __forceinline__ unsigned short f2bf(float f) {
  union { float f; unsigned u; } x; x.f = f;
  unsigned r = x.u + 0x7FFFu + ((x.u >> 16) & 1u);
  return (unsigned short)(r >> 16);
}
__device__ __forceinline__ float bf2f(unsigned s) {
  union { unsigned u; float f; } x; x.u = s << 16;
  return x.f;
}

// ---------------- prep: weights->bf16 + pos-embed adds + counter zero -------
__global__ void prep_all(const float* __restrict__ t_x, const float* __restrict__ audio,
                         const float* __restrict__ sp, const float* __restrict__ asp,
                         const float* __restrict__ tp, const float* __restrict__ atp,
                         const float* __restrict__ q_w, const float* __restrict__ kv_w,
                         const float* __restrict__ proj_w,
                         unsigned short* __restrict__ xb, unsigned short* __restrict__ ab,
                         unsigned short* __restrict__ wq, unsigned short* __restrict__ wkv,
                         unsigned short* __restrict__ wp, int* cnt, int total4) {
  const int n1 = 768 * 768 / 4, n2 = 1536 * 768 / 4;
  const int nconv = 2 * n1 + n2;
  int i = blockIdx.x * 256 + threadIdx.x;
  if (i < nconv) {
    const float* src; unsigned short* dst; int j = i;
    if (i < n1)           { src = q_w;    dst = wq;  }
    else if (i < n1 + n2) { src = kv_w;   dst = wkv; j = i - n1; }
    else                  { src = proj_w; dst = wp;  j = i - n1 - n2; }
    float4 v = *(const float4*)(src + (size_t)j * 4);
    ushort4 o;
    o.x = f2bf(v.x); o.y = f2bf(v.y); o.z = f2bf(v.z); o.w = f2bf(v.w);
    *(ushort4*)(dst + (size_t)j * 4) = o;
    return;
  }
  i -= nconv;
  if (i >= 2 * total4) {
    int iz = i - 2 * total4;
    if (cnt && iz < 624) cnt[iz] = 0;
    return;
  }
  if (i < total4) {
    int d4 = (i % 192) * 4;
    int row = i / 192;            // b*1568 + l
    int l = row % LQ;
    int t = l / 196, n = l % 196;
    float4 a  = *(const float4*)(t_x + (size_t)i * 4);
    float4 s  = *(const float4*)(sp + n * 768 + d4);
    float4 tt = *(const float4*)(tp + t * 768 + d4);
    ushort4 o;
    o.x = f2bf(a.x + s.x + tt.x);
    o.y = f2bf(a.y + s.y + tt.y);
    o.z = f2bf(a.z + s.z + tt.z);
    o.w = f2bf(a.w + s.w + tt.w);
    *(ushort4*)(xb + (size_t)i * 4) = o;
  } else {
    i -= total4;
    int d4 = (i % 192) * 4;
    int row = i / 192;            // b*1568 + (na*8+ta)
    int b = row / LK;
    int r2 = row % LK;
    int na = r2 >> 3, ta = r2 & 7;
    const float* src = audio + ((size_t)(2 + na) * 32 + b * 8 + ta) * 768 + d4;
    float4 a  = *(const float4*)src;
    float4 s  = *(const float4*)(asp + na * 768 + d4);
    float4 tt = *(const float4*)(atp + ta * 768 + d4);
    ushort4 o;
    o.x = f2bf(a.x + s.x + tt.x);
    o.y = f2bf(a.y + s.y + tt.y);
    o.z = f2bf(a.z + s.z + tt.z);
    o.w = f2bf(a.w + s.w + tt.w);
    *(ushort4*)(ab + (size_t)i * 4) = o;
  }
}

// ---------------- fused Q + KV projection GEMM -------------------------------
// m97 mainloop; epilogue repacks Q/K tiles through LDS for coalesced 16B stores.
__global__ __launch_bounds__(256, 4) void gemm_qkv(
    const unsigned short* __restrict__ xb, const unsigned short* __restrict__ ab,
    const unsigned short* __restrict__ wq, const unsigned short* __restrict__ wkv,
    const float* __restrict__ q_b, const float* __restrict__ kv_b,
    unsigned short* __restrict__ Qs, unsigned short* __restrict__ Kb,
    unsigned short* __restrict__ Vb) {
  __shared__ __align__(16) unsigned short sm[128 * 136];   // mainloop: As=sm, Bs=sm+8192
  unsigned short* As = sm;
  unsigned short* Bs = sm + 8192;
  const int tid = threadIdx.x;
  const int lane = tid & 63, wave = tid >> 6;
  const int wm = wave & 1, wn = wave >> 1;
  const int l15 = lane & 15, quad = lane >> 4;
  const int lr = tid >> 3, lc = (tid & 7) * 8;
  const int row0 = blockIdx.x * 128;
  const int y = blockIdx.y;
  const bool isQ = (y < 6);
  const int col0 = (isQ ? y : y - 6) * 128;
  const unsigned short* A = isQ ? xb : ab;
  const unsigned short* W = isQ ? wq : wkv;
  const float* bias = isQ ? q_b : kv_b;

  f4v acc[4][4] = {};
  for (int k0 = 0; k0 < 768; k0 += 64) {
    __syncthreads();
#pragma unroll
    for (int it = 0; it < 4; ++it) {
      int row = lr + it * 32;
      __builtin_amdgcn_global_load_lds(
          (const __attribute__((address_space(1))) unsigned int*)(A + (size_t)(row0 + row) * 768 + k0 + lc),
          (__attribute__((address_space(3))) unsigned int*)(As + row * 64 + lc), 16, 0, 0);
      __builtin_amdgcn_global_load_lds(
          (const __attribute__((address_space(1))) unsigned int*)(W + (size_t)(col0 + row) * 768 + k0 + lc),
          (__attribute__((address_space(3))) unsigned int*)(Bs + row * 64 + lc), 16, 0, 0);
    }
    __syncthreads();
#pragma unroll
    for (int kk = 0; kk < 2; ++kk) {
      s8v af[4], bf[4];
#pragma unroll
      for (int i = 0; i < 4; ++i) {
        af[i] = *(const s8v*)(As + (wm * 64 + i * 16 + l15) * 64 + kk * 32 + quad * 8);
        bf[i] = *(const s8v*)(Bs + (wn * 64 + i * 16 + l15) * 64 + kk * 32 + quad * 8);
      }
#pragma unroll
      for (int mi = 0; mi < 4; ++mi)
#pragma unroll
        for (int ni = 0; ni < 4; ++ni)
          acc[mi][ni] = __builtin_amdgcn_mfma_f32_16x16x32_bf16(af[mi], bf[ni],
                                                               acc[mi][ni], 0, 0, 0);
    }
  }

  if (!isQ && col0 >= 768) {
    // V block: direct packed 8B stores (already well-coalesced)
#pragma unroll
    for (int mi = 0; mi < 4; ++mi) {
      int rowg = row0 + wm * 64 + mi * 16 + quad * 4;
#pragma unroll
      for (int ni = 0; ni < 4; ++ni) {
        int colg = col0 + wn * 64 + ni * 16 + l15;
        float bv = bias[colg];
        int oo = colg - 768;
        int h = oo >> 6, hd = oo & 63;
        int b = rowg / LK, l0 = rowg - b * LK;   // rowg%4==0, no b-crossing
        ushort4 pk;
        pk.x = f2bf(acc[mi][ni][0] + bv);
        pk.y = f2bf(acc[mi][ni][1] + bv);
        pk.z = f2bf(acc[mi][ni][2] + bv);
        pk.w = f2bf(acc[mi][ni][3] + bv);
        *(ushort4*)(Vb + ((((size_t)b * NH + h) * 392 + (l0 >> 2)) * 64 + hd) * 4) = pk;
      }
    }
    return;
  }

  // Q or K block: repack through LDS (stride 136 => 16B-aligned rows), then
  // per-row cooperative uint4 stores (8 x uint4 = full 64-col half-row).
  const float sc = isQ ? 0.18033688011112042f : 1.0f;   // 0.125*log2(e) for exp2
  __syncthreads();
#pragma unroll
  for (int mi = 0; mi < 4; ++mi) {
    int rl = wm * 64 + mi * 16 + quad * 4;
#pragma unroll
    for (int ni = 0; ni < 4; ++ni) {
      int cl = wn * 64 + ni * 16 + l15;
      float bv = bias[col0 + cl];
#pragma unroll
      for (int r = 0; r < 4; ++r)
        sm[(rl + r) * 136 + cl] = f2bf((acc[mi][ni][r] + bv) * sc);
    }
  }
  __syncthreads();
  {
    int row = tid >> 1, half = tid & 1;
    int gl = row0 + row;
    int b = gl / LQ, l = gl - b * LQ;
    const unsigned short* src = sm + row * 136 + half * 64;
    unsigned short* dst;
    if (isQ) {
      dst = Qs + (((size_t)b * NH + (col0 >> 6) + half) * LQ + l) * 64;
    } else {
      int h = (col0 >> 6) + half;
      int tile = l / 112, rr = l - tile * 112;
      dst = Kb + (((size_t)b * NH + h) * 14 + tile) * 8064 + rr * 72;
    }
#pragma unroll
    for (int j = 0; j < 8; ++j)
      *(uint4*)(dst + j * 8) = *(const uint4*)(src + j * 8);
  }
}

// ---------------- output projection GEMM: 64x128 tiles, grid (98,6) ----------
__global__ __launch_bounds__(256, 4) void gemm_proj(
    const unsigned short* __restrict__ A, const unsigned short* __restrict__ W,
    const float* __restrict__ bias, float* __restrict__ out) {
  __shared__ __align__(16) unsigned short As[64 * 64];
  __shared__ __align__(16) unsigned short Bs[128 * 64];
  const int tid = threadIdx.x;
  const int lane = tid & 63, wave = tid >> 6;
  const int wm = wave & 1, wn = wave >> 1;
  const int l15 = lane & 15, quad = lane >> 4;
  const int row0 = blockIdx.x * 64;
  const int col0 = blockIdx.y * 128;
  const int lr = tid >> 3, lc = (tid & 7) * 8;

  f4v acc[2][4] = {};
  for (int k0 = 0; k0 < 768; k0 += 64) {
    __syncthreads();
#pragma unroll
    for (int it = 0; it < 2; ++it) {
      int row = lr + it * 32;
      __builtin_amdgcn_global_load_lds(
          (const __attribute__((address_space(1))) unsigned int*)(A + (size_t)(row0 + row) * 768 + k0 + lc),
          (__attribute__((address_space(3))) unsigned int*)(As + row * 64 + lc), 16, 0, 0);
    }
#pragma unroll
    for (int it = 0; it < 4; ++it) {
      int row = lr + it * 32;
      __builtin_amdgcn_global_load_lds(
          (const __attribute__((address_space(1))) unsigned int*)(W + (size_t)(col0 + row) * 768 + k0 + lc),
          (__attribute__((address_space(3))) unsigned int*)(Bs + row * 64 + lc), 16, 0, 0);
    }
    __syncthreads();
#pragma unroll
    for (int kk = 0; kk < 2; ++kk) {
      s8v af[2], bf[4];
#pragma unroll
      for (int i = 0; i < 2; ++i)
        af[i] = *(const s8v*)(As + (wm * 32 + i * 16 + l15) * 64 + kk * 32 + quad * 8);
#pragma unroll
      for (int i = 0; i < 4; ++i)
        bf[i] = *(const s8v*)(Bs + (wn * 64 + i * 16 + l15) * 64 + kk * 32 + quad * 8);
#pragma unroll
      for (int mi = 0; mi < 2; ++mi)
#pragma unroll
        for (int ni = 0; ni < 4; ++ni)
          acc[mi][ni] = __builtin_amdgcn_mfma_f32_16x16x32_bf16(af[mi], bf[ni],
                                                               acc[mi][ni], 0, 0, 0);
    }
  }

#pragma unroll
  for (int mi = 0; mi < 2; ++mi) {
    int rowg = row0 + wm * 32 + mi * 16 + quad * 4;
#pragma unroll
    for (int ni = 0; ni < 4; ++ni) {
      int colg = col0 + wn * 64 + ni * 16 + l15;
      float bv = bias[colg];
#pragma unroll
      for (int r = 0; r < 4; ++r)
        out[(size_t)(rowg + r) * 768 + colg] = acc[mi][ni][r] + bv;
    }
  }
}

// ---------------- flash attention, split-K + fused last-block merge ----------
// grid (13, 48, Z). Partials in MFMA-frag order (coalesced uint2 stores).
// If cnt != null: last block per (x,bh) merges all Z partials into Om.
__global__ __launch_bounds__(256, 4) void attn(
    const unsigned short* __restrict__ Q, const unsigned short* __restrict__ Kg,
    const unsigned short* __restrict__ Vsw,
    unsigned short* __restrict__ Op, float* __restrict__ Lp,
    unsigned short* __restrict__ Om, int* cnt, int Z) {
  __shared__ __align__(16) unsigned short Kl[112 * 72];
  __shared__ __align__(16) unsigned short Vl[112 * 64];
  __shared__ int do_merge_s;
  const int tid = threadIdx.x;
  const int lane = tid & 63, wave = tid >> 6;
  const int l15 = lane & 15, quad = lane >> 4;
  const int bh = blockIdx.y;
  const int q0 = blockIdx.x * 128;
  const int z = blockIdx.z;
  const int t0 = (z * 14) / Z, t1 = ((z + 1) * 14) / Z;
  const size_t base = (size_t)bh * LK * 64;

  s8v qf[2][2];
#pragma unroll
  for (int mt = 0; mt < 2; ++mt)
#pragma unroll
    for (int kk = 0; kk < 2; ++kk) {
      int row = q0 + wave * 32 + mt * 16 + l15;
      if (row > LQ - 1) row = LQ - 1;
      qf[mt][kk] = *(const s8v*)(Q + base + (size_t)row * 64 + kk * 32 + quad * 8);
    }

  f4v of[2][4] = {};
  float lr[2] = {0.0f, 0.0f};

  for (int kt = t0; kt < t1; ++kt) {
    __syncthreads();
    const unsigned short* Ksrc = Kg + ((size_t)bh * 14 + kt) * 8064;
    for (int c = tid; c < 1008; c += 256)
      __builtin_amdgcn_global_load_lds(
          (const __attribute__((address_space(1))) unsigned int*)(Ksrc + c * 8),
          (__attribute__((address_space(3))) unsigned int*)(Kl + c * 8), 16, 0, 0);
    const unsigned short* Vsrc = Vsw + base + (size_t)kt * 112 * 64;
    for (int c = tid; c < 896; c += 256)
      __builtin_amdgcn_global_load_lds(
          (const __attribute__((address_space(1))) unsigned int*)(Vsrc + c * 8),
          (__attribute__((address_space(3))) unsigned int*)(Vl + c * 8), 16, 0, 0);
    __syncthreads();

#pragma unroll
    for (int nt = 0; nt < 7; ++nt) {
      s8v kf0 = *(const s8v*)(Kl + (nt * 16 + l15) * 72 + quad * 8);
      s8v kf1 = *(const s8v*)(Kl + (nt * 16 + l15) * 72 + 32 + quad * 8);
      s4v pf[2];
#pragma unroll
      for (int mt = 0; mt < 2; ++mt) {
        f4v s = {};
        s = __builtin_amdgcn_mfma_f32_16x16x32_bf16(kf0, qf[mt][0], s, 0, 0, 0);
        s = __builtin_amdgcn_mfma_f32_16x16x32_bf16(kf1, qf[mt][1], s, 0, 0, 0);
        float p0 = __builtin_amdgcn_exp2f(s[0]);
        float p1 = __builtin_amdgcn_exp2f(s[1]);
        float p2 = __builtin_amdgcn_exp2f(s[2]);
        float p3 = __builtin_amdgcn_exp2f(s[3]);
        lr[mt] += (p0 + p1) + (p2 + p3);
        union { float f; unsigned u; } a0, a1, a2, a3;
        a0.f = p0; a1.f = p1; a2.f = p2; a3.f = p3;
        union { uint2 u; s4v s; } pk;
        pk.u.x = __builtin_amdgcn_perm(a1.u, a0.u, 0x07060302u);
        pk.u.y = __builtin_amdgcn_perm(a3.u, a2.u, 0x07060302u);
        pf[mt] = pk.s;
      }
#pragma unroll
      for (int nd = 0; nd < 4; ++nd) {
        s4v vf = *(const s4v*)(Vl + ((nt * 4 + quad) << 8) + ((nd * 16 + l15) << 2));
        of[0][nd] = __builtin_amdgcn_mfma_f32_16x16x16bf16_1k(pf[0], vf, of[0][nd], 0, 0, 0);
        of[1][nd] = __builtin_amdgcn_mfma_f32_16x16x16bf16_1k(pf[1], vf, of[1][nd], 0, 0, 0);
      }
    }
  }

#pragma unroll
  for (int mt = 0; mt < 2; ++mt) {
    lr[mt] += __shfl_xor(lr[mt], 16);
    lr[mt] += __shfl_xor(lr[mt], 32);
  }

  // frag-ordered partial store (coalesced uint2)
  const size_t bbase = (((size_t)z * 48 + bh) * 13 + blockIdx.x) * 8192;
#pragma unroll
  for (int mt = 0; mt < 2; ++mt) {
#pragma unroll
    for (int nd = 0; nd < 4; ++nd) {
      union { uint2 u; ushort4 s; } pk;
      pk.s.x = f2bf(of[mt][nd][0]);
      pk.s.y = f2bf(of[mt][nd][1]);
      pk.s.z = f2bf(of[mt][nd][2]);
      pk.s.w = f2bf(of[mt][nd][3]);
      *(uint2*)(Op + bbase + (size_t)(((wave * 2 + mt) * 4 + nd) * 256 + lane * 4)) = pk.u;
    }
    if (quad == 0)
      Lp[((size_t)z * 48 + bh) * LQP + q0 + wave * 32 + mt * 16 + l15] = lr[mt];
  }

  if (!cnt) return;   // unfused fallback: separate merge kernel runs

  __threadfence();    // release our partial writes (device scope)
  if (tid == 0)
    do_merge_s = (atomicAdd(&cnt[blockIdx.x * 48 + bh], 1) == Z - 1);
  __syncthreads();
  if (!do_merge_s) return;
  __threadfence();    // acquire other blocks' partials

  const int b = bh / NH, h = bh - b * NH;
#pragma unroll
  for (int k = 0; k < 8; ++k) {
    int c = tid + k * 256;
    int fo = c >> 6, lc2 = c & 63;
    int nd = fo & 3, wmm = fo >> 2;
    int rowl = (wmm >> 1) * 32 + (wmm & 1) * 16 + ((lc2 >> 4) << 2);
    int col = nd * 16 + (lc2 & 15);
    float a0 = 0, a1 = 0, a2 = 0, a3 = 0, s0 = 0, s1 = 0, s2 = 0, s3 = 0;
    for (int zz = 0; zz < Z; ++zz) {
      size_t zb = (size_t)zz * 48 + bh;
      uint2 v = *(const uint2*)(Op + (zb * 13 + blockIdx.x) * 8192 + (size_t)c * 4);
      a0 += bf2f(v.x & 0xffffu); a1 += bf2f(v.x >> 16);
      a2 += bf2f(v.y & 0xffffu); a3 += bf2f(v.y >> 16);
      float4 lv = *(const float4*)(Lp + zb * LQP + q0 + rowl);
      s0 += lv.x; s1 += lv.y; s2 += lv.z; s3 += lv.w;
    }
    int l0 = q0 + rowl;
    unsigned short* dst = Om + ((size_t)b * LQ + l0) * 768 + h * 64 + col;
    if (l0 + 0 < LQ) dst[0]        = f2bf(a0 / s0);
    if (l0 + 1 < LQ) dst[768]      = f2bf(a1 / s1);
    if (l0 + 2 < LQ) dst[2 * 768]  = f2bf(a2 / s2);
    if (l0 + 3 < LQ) dst[3 * 768]  = f2bf(a3 / s3);
  }
}

// ---------------- split-K merge (fallback path only) -------------------------
__global__ void attn_merge(const unsigned short* __restrict__ Op,
                           const float* __restrict__ Lp,
                           unsigned short* __restrict__ Om, int Z) {
  int i = blockIdx.x * 256 + threadIdx.x;   // 48*13*2048 exact
  int c = i & 2047;
  int t = i >> 11;
  int x = t % 13, bh = t / 13;
  int lane = c & 63, fo = c >> 6;
  int nd = fo & 3, wm = fo >> 2;
  int quad = lane >> 4, l15 = lane & 15;
  int rowl = (wm >> 1) * 32 + (wm & 1) * 16 + quad * 4;
  int col = nd * 16 + l15;
  float acc[4] = {};
  float ls[4] = {};
  for (int z = 0; z < Z; ++z) {
    size_t zb = (size_t)z * 48 + bh;
    uint2 v = *(const uint2*)(Op + (zb * 13 + x) * 8192 + (size_t)c * 4);
    acc[0] += bf2f(v.x & 0xffffu); acc[1] += bf2f(v.x >> 16);
    acc[2] += bf2f(v.y & 0xffffu); acc[3] += bf2f(v.y >> 16);
    float4 lv = *(const float4*)(Lp + zb * LQP + x * 128 + rowl);
    ls[0] += lv.x; ls[1] += lv.y; ls[2] += lv.z; ls[3] += lv.w;
  }
  int b = bh / NH, h = bh - b * NH;
#pragma unroll
  for (int r = 0; r < 4; ++r) {
    int l = x * 128 + rowl + r;
    if (l >= LQ) continue;
    Om[((size_t)b * LQ + l) * 768 + h * 64 + col] = f2bf(acc[r] / ls[r]);
  }
}

// ---------------- launcher ----------------
extern "C" void kernel_launch(void* const* d_in, const int* in_sizes, int n_in,
                              void* d_out, int out_size, void* d_ws, size_t ws_size,
                              hipStream_t stream) {
  const float* t_x    = (const float*)d_in[0];
  const float* audio  = (const float*)d_in[1];
  const float* sp     = (const float*)d_in[2];
  const float* asp    = (const float*)d_in[3];
  const float* tp     = (const float*)d_in[4];
  const float* atp    = (const float*)d_in[5];
  const float* q_w    = (const float*)d_in[6];
  const float* q_b    = (const float*)d_in[7];
  const float* kv_w   = (const float*)d_in[8];
  const float* kv_b   = (const float*)d_in[9];
  const float* proj_w = (const float*)d_in[10];
  const float* proj_b = (const float*)d_in[11];
  float* out = (float*)d_out;

  char* ws = (char*)d_ws;
  size_t off = 0;
  auto alloc = [&](size_t bytes) -> void* {
    void* p = ws + off;
    off += (bytes + 255) & ~(size_t)255;
    return p;
  };
  const size_t TOK = 6272;  // B*1568
  unsigned short* xb  = (unsigned short*)alloc(TOK * 768 * 2);
  unsigned short* ab  = (unsigned short*)alloc(TOK * 768 * 2);
  unsigned short* wq  = (unsigned short*)alloc(768 * 768 * 2);
  unsigned short* wkv = (unsigned short*)alloc(1536 * 768 * 2);
  unsigned short* wp  = (unsigned short*)alloc(768 * 768 * 2);
  unsigned short* Qs  = (unsigned short*)alloc(TOK * 768 * 2);        // [B,H,Lq,64] scaled
  unsigned short* Kb  = (unsigned short*)alloc((size_t)48 * 14 * 8064 * 2);  // K tiles 112x72
  unsigned short* Vb  = (unsigned short*)alloc(TOK * 768 * 2);        // [B,H,Lk/4,64,4]

  auto need = [&](int Zq) {
    return off + (size_t)Zq * 48 * 13 * 8192 * 2 + (size_t)Zq * 48 * LQP * 4 + 512;
  };
  int Z, fused;
  unsigned short *Op, *Om;
  float* Lp;
  int* cnt = nullptr;
  if (ws_size >= need(4) + 8192) {
    Z = 4; fused = 1;
    Op = (unsigned short*)alloc((size_t)4 * 48 * 13 * 8192 * 2);
    Lp = (float*)alloc((size_t)4 * 48 * LQP * 4);
    cnt = (int*)alloc(624 * 4);
    Om = xb;   // dead region during attn (Qs is still live for other blocks!)
  } else if (ws_size >= need(4)) {
    Z = 4; fused = 0;
    Op = (unsigned short*)alloc((size_t)4 * 48 * 13 * 8192 * 2);
    Lp = (float*)alloc((size_t)4 * 48 * LQP * 4);
    Om = Qs;
  } else {
    Z = 2; fused = 0;   // overlay dead xb..wq region
    Op = (unsigned short*)ws;
    Lp = (float*)(ws + (size_t)2 * 48 * 13 * 8192 * 2);
    Om = Qs;
  }

  dim3 blk(256);
  const int n1 = 768 * 768 / 4, n2 = 1536 * 768 / 4;
  int total4 = (int)(TOK * 192);
  int nprep = 2 * n1 + n2 + 2 * total4 + 624;
  prep_all<<<dim3((nprep + 255) / 256), blk, 0, stream>>>(
      t_x, audio, sp, asp, tp, atp, q_w, kv_w, proj_w, xb, ab, wq, wkv, wp, cnt, total4);

  gemm_qkv<<<dim3(49, 18), blk, 0, stream>>>(xb, ab, wq, wkv, q_b, kv_b, Qs, Kb, Vb);

  attn<<<dim3(13, 48, Z), blk, 0, stream>>>(Qs, Kb, Vb, Op, Lp, Om, cnt, Z);

  if (!fused)
    attn_merge<<<dim3(48 * 13 * 2048 / 256), blk, 0, stream>>>(Op, Lp, Om, Z);

  gemm_proj<<<dim3(98, 6), blk, 0, stream>>>(Om, wp, proj_b, out);
}

// Round 11
// 228.972 us; speedup vs baseline: 2.6657x; 2.6657x over previous
//
#include <hip/hip_runtime.h>

typedef short s8v __attribute__((ext_vector_type(8)));
typedef short s4v __attribute__((ext_vector_type(4)));
typedef float f4v __attribute__((ext_vector_type(4)));

#define LQ 1568
#define LK 1568
#define NH 12
#define LQP 1664   // 13*128 padded q-rows per head

__device__ __forceinline__ unsigned short f2bf(float f) {
  union { float f; unsigned u; } x; x.f = f;
  unsigned r = x.u + 0x7FFFu + ((x.u >> 16) & 1u);
  return (unsigned short)(r >> 16);
}
__device__ __forceinline__ float bf2f(unsigned s) {
  union { unsigned u; float f; } x; x.u = s << 16;
  return x.f;
}

// ---------------- prep: weights->bf16 + pos-embed adds ----------------------
__global__ void prep_all(const float* __restrict__ t_x, const float* __restrict__ audio,
                         const float* __restrict__ sp, const float* __restrict__ asp,
                         const float* __restrict__ tp, const float* __restrict__ atp,
                         const float* __restrict__ q_w, const float* __restrict__ kv_w,
                         const float* __restrict__ proj_w,
                         unsigned short* __restrict__ xb, unsigned short* __restrict__ ab,
                         unsigned short* __restrict__ wq, unsigned short* __restrict__ wkv,
                         unsigned short* __restrict__ wp, int total4) {
  const int n1 = 768 * 768 / 4, n2 = 1536 * 768 / 4;
  const int nconv = 2 * n1 + n2;
  int i = blockIdx.x * 256 + threadIdx.x;
  if (i < nconv) {
    const float* src; unsigned short* dst; int j = i;
    if (i < n1)           { src = q_w;    dst = wq;  }
    else if (i < n1 + n2) { src = kv_w;   dst = wkv; j = i - n1; }
    else                  { src = proj_w; dst = wp;  j = i - n1 - n2; }
    float4 v = *(const float4*)(src + (size_t)j * 4);
    ushort4 o;
    o.x = f2bf(v.x); o.y = f2bf(v.y); o.z = f2bf(v.z); o.w = f2bf(v.w);
    *(ushort4*)(dst + (size_t)j * 4) = o;
    return;
  }
  i -= nconv;
  if (i >= 2 * total4) return;
  if (i < total4) {
    int d4 = (i % 192) * 4;
    int row = i / 192;            // b*1568 + l
    int l = row % LQ;
    int t = l / 196, n = l % 196;
    float4 a  = *(const float4*)(t_x + (size_t)i * 4);
    float4 s  = *(const float4*)(sp + n * 768 + d4);
    float4 tt = *(const float4*)(tp + t * 768 + d4);
    ushort4 o;
    o.x = f2bf(a.x + s.x + tt.x);
    o.y = f2bf(a.y + s.y + tt.y);
    o.z = f2bf(a.z + s.z + tt.z);
    o.w = f2bf(a.w + s.w + tt.w);
    *(ushort4*)(xb + (size_t)i * 4) = o;
  } else {
    i -= total4;
    int d4 = (i % 192) * 4;
    int row = i / 192;            // b*1568 + (na*8+ta)
    int b = row / LK;
    int r2 = row % LK;
    int na = r2 >> 3, ta = r2 & 7;
    const float* src = audio + ((size_t)(2 + na) * 32 + b * 8 + ta) * 768 + d4;
    float4 a  = *(const float4*)src;
    float4 s  = *(const float4*)(asp + na * 768 + d4);
    float4 tt = *(const float4*)(atp + ta * 768 + d4);
    ushort4 o;
    o.x = f2bf(a.x + s.x + tt.x);
    o.y = f2bf(a.y + s.y + tt.y);
    o.z = f2bf(a.z + s.z + tt.z);
    o.w = f2bf(a.w + s.w + tt.w);
    *(ushort4*)(ab + (size_t)i * 4) = o;
  }
}

// ---------------- fused Q + KV projection GEMM -------------------------------
// m97 mainloop; epilogue repacks Q/K tiles through LDS for coalesced 16B stores.
__global__ __launch_bounds__(256, 4) void gemm_qkv(
    const unsigned short* __restrict__ xb, const unsigned short* __restrict__ ab,
    const unsigned short* __restrict__ wq, const unsigned short* __restrict__ wkv,
    const float* __restrict__ q_b, const float* __restrict__ kv_b,
    unsigned short* __restrict__ Qs, unsigned short* __restrict__ Kb,
    unsigned short* __restrict__ Vb) {
  __shared__ __align__(16) unsigned short sm[128 * 136];   // mainloop: As=sm, Bs=sm+8192
  unsigned short* As = sm;
  unsigned short* Bs = sm + 8192;
  const int tid = threadIdx.x;
  const int lane = tid & 63, wave = tid >> 6;
  const int wm = wave & 1, wn = wave >> 1;
  const int l15 = lane & 15, quad = lane >> 4;
  const int lr = tid >> 3, lc = (tid & 7) * 8;
  const int row0 = blockIdx.x * 128;
  const int y = blockIdx.y;
  const bool isQ = (y < 6);
  const int col0 = (isQ ? y : y - 6) * 128;
  const unsigned short* A = isQ ? xb : ab;
  const unsigned short* W = isQ ? wq : wkv;
  const float* bias = isQ ? q_b : kv_b;

  f4v acc[4][4] = {};
  for (int k0 = 0; k0 < 768; k0 += 64) {
    __syncthreads();
#pragma unroll
    for (int it = 0; it < 4; ++it) {
      int row = lr + it * 32;
      __builtin_amdgcn_global_load_lds(
          (const __attribute__((address_space(1))) unsigned int*)(A + (size_t)(row0 + row) * 768 + k0 + lc),
          (__attribute__((address_space(3))) unsigned int*)(As + row * 64 + lc), 16, 0, 0);
      __builtin_amdgcn_global_load_lds(
          (const __attribute__((address_space(1))) unsigned int*)(W + (size_t)(col0 + row) * 768 + k0 + lc),
          (__attribute__((address_space(3))) unsigned int*)(Bs + row * 64 + lc), 16, 0, 0);
    }
    __syncthreads();
#pragma unroll
    for (int kk = 0; kk < 2; ++kk) {
      s8v af[4], bf[4];
#pragma unroll
      for (int i = 0; i < 4; ++i) {
        af[i] = *(const s8v*)(As + (wm * 64 + i * 16 + l15) * 64 + kk * 32 + quad * 8);
        bf[i] = *(const s8v*)(Bs + (wn * 64 + i * 16 + l15) * 64 + kk * 32 + quad * 8);
      }
#pragma unroll
      for (int mi = 0; mi < 4; ++mi)
#pragma unroll
        for (int ni = 0; ni < 4; ++ni)
          acc[mi][ni] = __builtin_amdgcn_mfma_f32_16x16x32_bf16(af[mi], bf[ni],
                                                               acc[mi][ni], 0, 0, 0);
    }
  }

  if (!isQ && col0 >= 768) {
    // V block: direct packed 8B stores (already well-coalesced)
#pragma unroll
    for (int mi = 0; mi < 4; ++mi) {
      int rowg = row0 + wm * 64 + mi * 16 + quad * 4;
#pragma unroll
      for (int ni = 0; ni < 4; ++ni) {
        int colg = col0 + wn * 64 + ni * 16 + l15;
        float bv = bias[colg];
        int oo = colg - 768;
        int h = oo >> 6, hd = oo & 63;
        int b = rowg / LK, l0 = rowg - b * LK;   // rowg%4==0, no b-crossing
        ushort4 pk;
        pk.x = f2bf(acc[mi][ni][0] + bv);
        pk.y = f2bf(acc[mi][ni][1] + bv);
        pk.z = f2bf(acc[mi][ni][2] + bv);
        pk.w = f2bf(acc[mi][ni][3] + bv);
        *(ushort4*)(Vb + ((((size_t)b * NH + h) * 392 + (l0 >> 2)) * 64 + hd) * 4) = pk;
      }
    }
    return;
  }

  // Q or K block: repack through LDS (stride 136 => 16B-aligned rows), then
  // per-row cooperative uint4 stores (8 x uint4 = full 64-col half-row).
  const float sc = isQ ? 0.18033688011112042f : 1.0f;   // 0.125*log2(e) for exp2
  __syncthreads();
#pragma unroll
  for (int mi = 0; mi < 4; ++mi) {
    int rl = wm * 64 + mi * 16 + quad * 4;
#pragma unroll
    for (int ni = 0; ni < 4; ++ni) {
      int cl = wn * 64 + ni * 16 + l15;
      float bv = bias[col0 + cl];
#pragma unroll
      for (int r = 0; r < 4; ++r)
        sm[(rl + r) * 136 + cl] = f2bf((acc[mi][ni][r] + bv) * sc);
    }
  }
  __syncthreads();
  {
    int row = tid >> 1, half = tid & 1;
    int gl = row0 + row;
    int b = gl / LQ, l = gl - b * LQ;
    const unsigned short* src = sm + row * 136 + half * 64;
    unsigned short* dst;
    if (isQ) {
      dst = Qs + (((size_t)b * NH + (col0 >> 6) + half) * LQ + l) * 64;
    } else {
      int h = (col0 >> 6) + half;
      int tile = l / 112, rr = l - tile * 112;
      dst = Kb + (((size_t)b * NH + h) * 14 + tile) * 8064 + rr * 72;
    }
#pragma unroll
    for (int j = 0; j < 8; ++j)
      *(uint4*)(dst + j * 8) = *(const uint4*)(src + j * 8);
  }
}

// ---------------- output projection GEMM: 64x128 tiles, grid (98,6) ----------
__global__ __launch_bounds__(256, 4) void gemm_proj(
    const unsigned short* __restrict__ A, const unsigned short* __restrict__ W,
    const float* __restrict__ bias, float* __restrict__ out) {
  __shared__ __align__(16) unsigned short As[64 * 64];
  __shared__ __align__(16) unsigned short Bs[128 * 64];
  const int tid = threadIdx.x;
  const int lane = tid & 63, wave = tid >> 6;
  const int wm = wave & 1, wn = wave >> 1;
  const int l15 = lane & 15, quad = lane >> 4;
  const int row0 = blockIdx.x * 64;
  const int col0 = blockIdx.y * 128;
  const int lr = tid >> 3, lc = (tid & 7) * 8;

  f4v acc[2][4] = {};
  for (int k0 = 0; k0 < 768; k0 += 64) {
    __syncthreads();
#pragma unroll
    for (int it = 0; it < 2; ++it) {
      int row = lr + it * 32;
      __builtin_amdgcn_global_load_lds(
          (const __attribute__((address_space(1))) unsigned int*)(A + (size_t)(row0 + row) * 768 + k0 + lc),
          (__attribute__((address_space(3))) unsigned int*)(As + row * 64 + lc), 16, 0, 0);
    }
#pragma unroll
    for (int it = 0; it < 4; ++it) {
      int row = lr + it * 32;
      __builtin_amdgcn_global_load_lds(
          (const __attribute__((address_space(1))) unsigned int*)(W + (size_t)(col0 + row) * 768 + k0 + lc),
          (__attribute__((address_space(3))) unsigned int*)(Bs + row * 64 + lc), 16, 0, 0);
    }
    __syncthreads();
#pragma unroll
    for (int kk = 0; kk < 2; ++kk) {
      s8v af[2], bf[4];
#pragma unroll
      for (int i = 0; i < 2; ++i)
        af[i] = *(const s8v*)(As + (wm * 32 + i * 16 + l15) * 64 + kk * 32 + quad * 8);
#pragma unroll
      for (int i = 0; i < 4; ++i)
        bf[i] = *(const s8v*)(Bs + (wn * 64 + i * 16 + l15) * 64 + kk * 32 + quad * 8);
#pragma unroll
      for (int mi = 0; mi < 2; ++mi)
#pragma unroll
        for (int ni = 0; ni < 4; ++ni)
          acc[mi][ni] = __builtin_amdgcn_mfma_f32_16x16x32_bf16(af[mi], bf[ni],
                                                               acc[mi][ni], 0, 0, 0);
    }
  }

#pragma unroll
  for (int mi = 0; mi < 2; ++mi) {
    int rowg = row0 + wm * 32 + mi * 16 + quad * 4;
#pragma unroll
    for (int ni = 0; ni < 4; ++ni) {
      int colg = col0 + wn * 64 + ni * 16 + l15;
      float bv = bias[colg];
#pragma unroll
      for (int r = 0; r < 4; ++r)
        out[(size_t)(rowg + r) * 768 + colg] = acc[mi][ni][r] + bv;
    }
  }
}

// ---------------- flash attention, split-K over Z slices ---------------------
// grid (13, 48, Z). Partials in MFMA-frag order (coalesced uint2 stores).
// Merge is a separate kernel: the kernel-launch boundary provides cross-XCD
// coherence for free (in-kernel threadfence merge = L2-flush storm, R10).
__global__ __launch_bounds__(256, 4) void attn(
    const unsigned short* __restrict__ Q, const unsigned short* __restrict__ Kg,
    const unsigned short* __restrict__ Vsw,
    unsigned short* __restrict__ Op, float* __restrict__ Lp, int Z) {
  __shared__ __align__(16) unsigned short Kl[112 * 72];
  __shared__ __align__(16) unsigned short Vl[112 * 64];
  const int tid = threadIdx.x;
  const int lane = tid & 63, wave = tid >> 6;
  const int l15 = lane & 15, quad = lane >> 4;
  const int bh = blockIdx.y;
  const int q0 = blockIdx.x * 128;
  const int z = blockIdx.z;
  const int t0 = (z * 14) / Z, t1 = ((z + 1) * 14) / Z;
  const size_t base = (size_t)bh * LK * 64;

  s8v qf[2][2];
#pragma unroll
  for (int mt = 0; mt < 2; ++mt)
#pragma unroll
    for (int kk = 0; kk < 2; ++kk) {
      int row = q0 + wave * 32 + mt * 16 + l15;
      if (row > LQ - 1) row = LQ - 1;
      qf[mt][kk] = *(const s8v*)(Q + base + (size_t)row * 64 + kk * 32 + quad * 8);
    }

  f4v of[2][4] = {};
  float lr[2] = {0.0f, 0.0f};

  for (int kt = t0; kt < t1; ++kt) {
    __syncthreads();
    const unsigned short* Ksrc = Kg + ((size_t)bh * 14 + kt) * 8064;
    for (int c = tid; c < 1008; c += 256)
      __builtin_amdgcn_global_load_lds(
          (const __attribute__((address_space(1))) unsigned int*)(Ksrc + c * 8),
          (__attribute__((address_space(3))) unsigned int*)(Kl + c * 8), 16, 0, 0);
    const unsigned short* Vsrc = Vsw + base + (size_t)kt * 112 * 64;
    for (int c = tid; c < 896; c += 256)
      __builtin_amdgcn_global_load_lds(
          (const __attribute__((address_space(1))) unsigned int*)(Vsrc + c * 8),
          (__attribute__((address_space(3))) unsigned int*)(Vl + c * 8), 16, 0, 0);
    __syncthreads();

#pragma unroll
    for (int nt = 0; nt < 7; ++nt) {
      s8v kf0 = *(const s8v*)(Kl + (nt * 16 + l15) * 72 + quad * 8);
      s8v kf1 = *(const s8v*)(Kl + (nt * 16 + l15) * 72 + 32 + quad * 8);
      s4v pf[2];
#pragma unroll
      for (int mt = 0; mt < 2; ++mt) {
        f4v s = {};
        s = __builtin_amdgcn_mfma_f32_16x16x32_bf16(kf0, qf[mt][0], s, 0, 0, 0);
        s = __builtin_amdgcn_mfma_f32_16x16x32_bf16(kf1, qf[mt][1], s, 0, 0, 0);
        float p0 = __builtin_amdgcn_exp2f(s[0]);
        float p1 = __builtin_amdgcn_exp2f(s[1]);
        float p2 = __builtin_amdgcn_exp2f(s[2]);
        float p3 = __builtin_amdgcn_exp2f(s[3]);
        lr[mt] += (p0 + p1) + (p2 + p3);
        union { float f; unsigned u; } a0, a1, a2, a3;
        a0.f = p0; a1.f = p1; a2.f = p2; a3.f = p3;
        union { uint2 u; s4v s; } pk;
        pk.u.x = __builtin_amdgcn_perm(a1.u, a0.u, 0x07060302u);
        pk.u.y = __builtin_amdgcn_perm(a3.u, a2.u, 0x07060302u);
        pf[mt] = pk.s;
      }
#pragma unroll
      for (int nd = 0; nd < 4; ++nd) {
        s4v vf = *(const s4v*)(Vl + ((nt * 4 + quad) << 8) + ((nd * 16 + l15) << 2));
        of[0][nd] = __builtin_amdgcn_mfma_f32_16x16x16bf16_1k(pf[0], vf, of[0][nd], 0, 0, 0);
        of[1][nd] = __builtin_amdgcn_mfma_f32_16x16x16bf16_1k(pf[1], vf, of[1][nd], 0, 0, 0);
      }
    }
  }

#pragma unroll
  for (int mt = 0; mt < 2; ++mt) {
    lr[mt] += __shfl_xor(lr[mt], 16);
    lr[mt] += __shfl_xor(lr[mt], 32);
  }

  // frag-ordered partial store (coalesced uint2)
  const size_t bbase = (((size_t)z * 48 + bh) * 13 + blockIdx.x) * 8192;
#pragma unroll
  for (int mt = 0; mt < 2; ++mt) {
#pragma unroll
    for (int nd = 0; nd < 4; ++nd) {
      union { uint2 u; ushort4 s; } pk;
      pk.s.x = f2bf(of[mt][nd][0]);
      pk.s.y = f2bf(of[mt][nd][1]);
      pk.s.z = f2bf(of[mt][nd][2]);
      pk.s.w = f2bf(of[mt][nd][3]);
      *(uint2*)(Op + bbase + (size_t)(((wave * 2 + mt) * 4 + nd) * 256 + lane * 4)) = pk.u;
    }
    if (quad == 0)
      Lp[((size_t)z * 48 + bh) * LQP + q0 + wave * 32 + mt * 16 + l15] = lr[mt];
  }
}

// ---------------- split-K merge (frag-order in, row-major out) ---------------
__global__ void attn_merge(const unsigned short* __restrict__ Op,
                           const float* __restrict__ Lp,
                           unsigned short* __restrict__ Om, int Z) {
  int i = blockIdx.x * 256 + threadIdx.x;   // 48*13*2048 exact
  int c = i & 2047;
  int t = i >> 11;
  int x = t % 13, bh = t / 13;
  int lane = c & 63, fo = c >> 6;
  int nd = fo & 3, wm = fo >> 2;
  int quad = lane >> 4, l15 = lane & 15;
  int rowl = (wm >> 1) * 32 + (wm & 1) * 16 + quad * 4;
  int col = nd * 16 + l15;
  float acc[4] = {};
  float ls[4] = {};
  for (int z = 0; z < Z; ++z) {
    size_t zb = (size_t)z * 48 + bh;
    uint2 v = *(const uint2*)(Op + (zb * 13 + x) * 8192 + (size_t)c * 4);
    acc[0] += bf2f(v.x & 0xffffu); acc[1] += bf2f(v.x >> 16);
    acc[2] += bf2f(v.y & 0xffffu); acc[3] += bf2f(v.y >> 16);
    float4 lv = *(const float4*)(Lp + zb * LQP + x * 128 + rowl);
    ls[0] += lv.x; ls[1] += lv.y; ls[2] += lv.z; ls[3] += lv.w;
  }
  int b = bh / NH, h = bh - b * NH;
#pragma unroll
  for (int r = 0; r < 4; ++r) {
    int l = x * 128 + rowl + r;
    if (l >= LQ) continue;
    Om[((size_t)b * LQ + l) * 768 + h * 64 + col] = f2bf(acc[r] / ls[r]);
  }
}

// ---------------- launcher ----------------
extern "C" void kernel_launch(void* const* d_in, const int* in_sizes, int n_in,
                              void* d_out, int out_size, void* d_ws, size_t ws_size,
                              hipStream_t stream) {
  const float* t_x    = (const float*)d_in[0];
  const float* audio  = (const float*)d_in[1];
  const float* sp     = (const float*)d_in[2];
  const float* asp    = (const float*)d_in[3];
  const float* tp     = (const float*)d_in[4];
  const float* atp    = (const float*)d_in[5];
  const float* q_w    = (const float*)d_in[6];
  const float* q_b    = (const float*)d_in[7];
  const float* kv_w   = (const float*)d_in[8];
  const float* kv_b   = (const float*)d_in[9];
  const float* proj_w = (const float*)d_in[10];
  const float* proj_b = (const float*)d_in[11];
  float* out = (float*)d_out;

  char* ws = (char*)d_ws;
  size_t off = 0;
  auto alloc = [&](size_t bytes) -> void* {
    void* p = ws + off;
    off += (bytes + 255) & ~(size_t)255;
    return p;
  };
  const size_t TOK = 6272;  // B*1568
  unsigned short* xb  = (unsigned short*)alloc(TOK * 768 * 2);
  unsigned short* ab  = (unsigned short*)alloc(TOK * 768 * 2);
  unsigned short* wq  = (unsigned short*)alloc(768 * 768 * 2);
  unsigned short* wkv = (unsigned short*)alloc(1536 * 768 * 2);
  unsigned short* wp  = (unsigned short*)alloc(768 * 768 * 2);
  unsigned short* Qs  = (unsigned short*)alloc(TOK * 768 * 2);        // [B,H,Lq,64] scaled
  unsigned short* Kb  = (unsigned short*)alloc((size_t)48 * 14 * 8064 * 2);  // K tiles 112x72
  unsigned short* Vb  = (unsigned short*)alloc(TOK * 768 * 2);        // [B,H,Lk/4,64,4]

  auto need = [&](int Zq) {
    return off + (size_t)Zq * 48 * 13 * 8192 * 2 + (size_t)Zq * 48 * LQP * 4 + 512;
  };
  int Z;
  unsigned short *Op, *Om;
  float* Lp;
  if (ws_size >= need(4)) {
    Z = 4;
    Op = (unsigned short*)alloc((size_t)4 * 48 * 13 * 8192 * 2);
    Lp = (float*)alloc((size_t)4 * 48 * LQP * 4);
  } else {
    Z = 2;   // overlay dead xb..wq region
    Op = (unsigned short*)ws;
    Lp = (float*)(ws + (size_t)2 * 48 * 13 * 8192 * 2);
  }
  Om = Qs;   // merged O reuses dead Qs region

  dim3 blk(256);
  const int n1 = 768 * 768 / 4, n2 = 1536 * 768 / 4;
  int total4 = (int)(TOK * 192);
  int nprep = 2 * n1 + n2 + 2 * total4;
  prep_all<<<dim3((nprep + 255) / 256), blk, 0, stream>>>(
      t_x, audio, sp, asp, tp, atp, q_w, kv_w, proj_w, xb, ab, wq, wkv, wp, total4);

  gemm_qkv<<<dim3(49, 18), blk, 0, stream>>>(xb, ab, wq, wkv, q_b, kv_b, Qs, Kb, Vb);

  attn<<<dim3(13, 48, Z), blk, 0, stream>>>(Qs, Kb, Vb, Op, Lp, Z);

  attn_merge<<<dim3(48 * 13 * 2048 / 256), blk, 0, stream>>>(Op, Lp, Om, Z);

  gemm_proj<<<dim3(98, 6), blk, 0, stream>>>(Om, wp, proj_b, out);
}